// Round 3
// baseline (209.851 us; speedup 1.0000x reference)
//
#include <hip/hip_runtime.h>
#include <math.h>

// BinaryTreeRNN: h = x@W_leaf.T + b_leaf (N,8), then 3 tree-combine levels
// (8->4->2->1), out = h[:,0]. Memory floor: 64B read + 4B write per row
// => ~22 us at 6.3 TB/s. VALU floor ~7 us. Should be memory-bound.
//
// R1: grid-stride + hoisted W regs: 211 us. R2: one-row-per-thread + prep
// kernel: 206 us (-2%) => spill theory WRONG. Top-5 dispatches are all
// harness 512MB ws-poison fills (73 us @87% peak); our kernel is <72 us but
// still ~3x its floor. New theory: libm sinf Payne-Hanek slow path --
// combine args reach O(1e4..1e5) (l*r compounds), |x|>=2^16 lanes drag whole
// waves through the divergent reduction, 3 sins/row. Fix: __sinf (native
// v_sin_f32, branchless); err ~|x|*2^-24 rad << 19.44 threshold.

// ws layout (floats):
// [0:4) A2 [4:8) B2 [8:12) C2 [12:16) D2
// [16:18) A1 [18:20) B1 [20:22) C1 [22:24) D1
// [24] A0 [25] B0 [26] C0 [27] D0
// [28:36) b_leaf
__global__ void prep_kernel(
    const float* __restrict__ b_leaf,
    const float* __restrict__ w0, const float* __restrict__ w1,
    const float* __restrict__ w2,
    const float* __restrict__ b0, const float* __restrict__ b1,
    const float* __restrict__ b2,
    const float* __restrict__ om0, const float* __restrict__ om1,
    const float* __restrict__ om2,
    float* __restrict__ ws)
{
    for (int j = 0; j < 4; ++j) {
        float o0 = om2[j*4+0], o1 = om2[j*4+1], o2 = om2[j*4+2], o3 = om2[j*4+3];
        float m  = fmaxf(fmaxf(o0, o1), fmaxf(o2, o3));
        float e0 = expf(o0-m), e1 = expf(o1-m), e2 = expf(o2-m), e3 = expf(o3-m);
        float inv = 1.0f / (e0+e1+e2+e3);
        float wj = w2[j];
        ws[0+j]  = wj * (e0+e3) * inv;
        ws[4+j]  = wj * e1 * inv;
        ws[8+j]  = wj * e2 * inv;
        ws[12+j] = b2[j];
    }
    for (int j = 0; j < 2; ++j) {
        float o0 = om1[j*4+0], o1 = om1[j*4+1], o2 = om1[j*4+2], o3 = om1[j*4+3];
        float m  = fmaxf(fmaxf(o0, o1), fmaxf(o2, o3));
        float e0 = expf(o0-m), e1 = expf(o1-m), e2 = expf(o2-m), e3 = expf(o3-m);
        float inv = 1.0f / (e0+e1+e2+e3);
        float wj = w1[j];
        ws[16+j] = wj * (e0+e3) * inv;
        ws[18+j] = wj * e1 * inv;
        ws[20+j] = wj * e2 * inv;
        ws[22+j] = b1[j];
    }
    {
        float o0 = om0[0], o1 = om0[1], o2 = om0[2], o3 = om0[3];
        float m  = fmaxf(fmaxf(o0, o1), fmaxf(o2, o3));
        float e0 = expf(o0-m), e1 = expf(o1-m), e2 = expf(o2-m), e3 = expf(o3-m);
        float inv = 1.0f / (e0+e1+e2+e3);
        float wj = w0[0];
        ws[24] = wj * (e0+e3) * inv;
        ws[25] = wj * e1 * inv;
        ws[26] = wj * e2 * inv;
        ws[27] = b0[0];
    }
    for (int j = 0; j < 8; ++j) ws[28+j] = b_leaf[j];
}

// branchless sin: exact enough for |x| up to ~1e6 given 19.44 abs threshold
__device__ __forceinline__ float fast_sin(float s) {
    return __sinf(s);   // native v_sin_f32 path, no Payne-Hanek branch
}

__global__ __launch_bounds__(256) void tree_rnn_kernel(
    const float* __restrict__ x,
    const float* __restrict__ W_leaf,
    const float* __restrict__ coef,
    float* __restrict__ out,
    int n)
{
    int i = blockIdx.x * 256 + threadIdx.x;
    if (i >= n) return;

    const float4* xr = reinterpret_cast<const float4*>(x) + (long long)i * 4;
    float4 va = xr[0];
    float4 vb = xr[1];
    float4 vc = xr[2];
    float4 vd = xr[3];
    float xv[16] = {va.x, va.y, va.z, va.w,
                    vb.x, vb.y, vb.z, vb.w,
                    vc.x, vc.y, vc.z, vc.w,
                    vd.x, vd.y, vd.z, vd.w};

    // leaf matvec (W_leaf wave-uniform -> scalar loads)
    float h[8];
#pragma unroll
    for (int j = 0; j < 8; ++j) {
        float acc = coef[28 + j];
#pragma unroll
        for (int v = 0; v < 16; ++v)
            acc = fmaf(xv[v], W_leaf[j * 16 + v], acc);
        h[j] = acc;
    }

    // level 2: 8 -> 4
    float g4[4];
#pragma unroll
    for (int j = 0; j < 4; ++j) {
        float l = h[2*j], r = h[2*j+1];
        float s = l + r;
        g4[j] = fmaf(coef[0+j], s,
                 fmaf(coef[4+j], l * r,
                  fmaf(coef[8+j], fast_sin(s), coef[12+j])));
    }

    // level 1: 4 -> 2
    float g2[2];
#pragma unroll
    for (int j = 0; j < 2; ++j) {
        float l = g4[2*j], r = g4[2*j+1];
        float s = l + r;
        g2[j] = fmaf(coef[16+j], s,
                 fmaf(coef[18+j], l * r,
                  fmaf(coef[20+j], fast_sin(s), coef[22+j])));
    }

    // level 0: 2 -> 1
    {
        float l = g2[0], r = g2[1];
        float s = l + r;
        out[i] = fmaf(coef[24], s,
                  fmaf(coef[25], l * r,
                   fmaf(coef[26], fast_sin(s), coef[27])));
    }
}

extern "C" void kernel_launch(void* const* d_in, const int* in_sizes, int n_in,
                              void* d_out, int out_size, void* d_ws, size_t ws_size,
                              hipStream_t stream) {
    const float* x      = (const float*)d_in[0];
    const float* W_leaf = (const float*)d_in[1];
    const float* b_leaf = (const float*)d_in[2];
    const float* w0     = (const float*)d_in[3];
    const float* w1     = (const float*)d_in[4];
    const float* w2     = (const float*)d_in[5];
    const float* b0     = (const float*)d_in[6];
    const float* b1     = (const float*)d_in[7];
    const float* b2     = (const float*)d_in[8];
    const float* om0    = (const float*)d_in[9];
    const float* om1    = (const float*)d_in[10];
    const float* om2    = (const float*)d_in[11];
    float* out  = (float*)d_out;
    float* coef = (float*)d_ws;   // 36 floats

    int n = in_sizes[0] / 16;

    prep_kernel<<<1, 1, 0, stream>>>(b_leaf, w0, w1, w2, b0, b1, b2,
                                     om0, om1, om2, coef);

    int block = 256;
    int grid = (n + block - 1) / block;
    tree_rnn_kernel<<<grid, block, 0, stream>>>(x, W_leaf, coef, out, n);
}

// Round 4
// 199.938 us; speedup vs baseline: 1.0496x; 1.0496x over previous
//
#include <hip/hip_runtime.h>
#include <math.h>

// BinaryTreeRNN: h = x@W_leaf.T + b_leaf (N,8), 3 tree-combine levels
// (8->4->2->1), out = h[:,0]. Controllable floor: 128MB read + 8MB write
// => ~22 us at 6.3 TB/s (less if x is LLC-resident from the harness restore).
//
// R1-R3 lesson: three structurally different kernels all measure 206-211 us.
// Top-5 dispatches are ALWAYS harness 512MB ws-poison fills (73 us @87% HBM
// peak); our kernel is <72 us and invisible. Fixed per-iteration reset cost
// (ws poison 73us + x restore ~40us + 12 small restores ~60us overhead)
// ~ 180 us dominates dur_us. Controllable share ~25-35 us, already near the
// HBM floor. This round: last lever -- fuse prep into the main kernel via
// block-level LDS prep (drops one graph node + the d_ws round-trip).

__global__ __launch_bounds__(256) void tree_rnn_fused(
    const float* __restrict__ x,
    const float* __restrict__ W_leaf,
    const float* __restrict__ b_leaf,
    const float* __restrict__ w0, const float* __restrict__ w1,
    const float* __restrict__ w2,
    const float* __restrict__ b0, const float* __restrict__ b1,
    const float* __restrict__ b2,
    const float* __restrict__ om0, const float* __restrict__ om1,
    const float* __restrict__ om2,
    float* __restrict__ out,
    int n)
{
    // LDS coef table:
    // [0:4) A2 [4:8) B2 [8:12) C2 [12:16) D2
    // [16:18) A1 [18:20) B1 [20:22) C1 [22:24) D1
    // [24] A0 [25] B0 [26] C0 [27] D0
    // [28:36) b_leaf
    __shared__ float cf[36];

    int t = threadIdx.x;
    if (t < 7) {
        // node t: t in [0,4) -> level2 node t; t in [4,6) -> level1 node t-4;
        // t == 6 -> level0.
        const float* om; float wj, bj; int base, strd;
        if (t < 4)      { om = om2 + t * 4;       wj = w2[t];   bj = b2[t];   base = t;      strd = 4; }
        else if (t < 6) { om = om1 + (t - 4) * 4; wj = w1[t-4]; bj = b1[t-4]; base = 16+(t-4); strd = 2; }
        else            { om = om0;               wj = w0[0];   bj = b0[0];   base = 24;     strd = 1; }
        float o0 = om[0], o1 = om[1], o2 = om[2], o3 = om[3];
        float m  = fmaxf(fmaxf(o0, o1), fmaxf(o2, o3));
        float e0 = expf(o0-m), e1 = expf(o1-m), e2 = expf(o2-m), e3 = expf(o3-m);
        float inv = 1.0f / (e0+e1+e2+e3);
        cf[base]          = wj * (e0+e3) * inv;  // A
        cf[base+strd]     = wj * e1 * inv;       // B
        cf[base+2*strd]   = wj * e2 * inv;       // C
        cf[base+3*strd]   = bj;                  // D
    } else if (t >= 8 && t < 16) {
        cf[28 + (t - 8)] = b_leaf[t - 8];
    }
    __syncthreads();

    int i = blockIdx.x * 256 + t;
    if (i >= n) return;

    // coalesced row load: 4x dwordx4 per lane, wave covers 4KB contiguous
    const float4* xr = reinterpret_cast<const float4*>(x) + (long long)i * 4;
    float4 va = xr[0];
    float4 vb = xr[1];
    float4 vc = xr[2];
    float4 vd = xr[3];
    float xv[16] = {va.x, va.y, va.z, va.w,
                    vb.x, vb.y, vb.z, vb.w,
                    vc.x, vc.y, vc.z, vc.w,
                    vd.x, vd.y, vd.z, vd.w};

    // leaf matvec (W_leaf wave-uniform -> scalar loads, L1-resident)
    float h[8];
#pragma unroll
    for (int j = 0; j < 8; ++j) {
        float acc = cf[28 + j];
#pragma unroll
        for (int v = 0; v < 16; ++v)
            acc = fmaf(xv[v], W_leaf[j * 16 + v], acc);
        h[j] = acc;
    }

    // level 2: 8 -> 4   (LDS reads are same-address broadcasts: conflict-free)
    float g4[4];
#pragma unroll
    for (int j = 0; j < 4; ++j) {
        float l = h[2*j], r = h[2*j+1];
        float s = l + r;
        g4[j] = fmaf(cf[0+j], s,
                 fmaf(cf[4+j], l * r,
                  fmaf(cf[8+j], __sinf(s), cf[12+j])));
    }

    // level 1: 4 -> 2
    float g2[2];
#pragma unroll
    for (int j = 0; j < 2; ++j) {
        float l = g4[2*j], r = g4[2*j+1];
        float s = l + r;
        g2[j] = fmaf(cf[16+j], s,
                 fmaf(cf[18+j], l * r,
                  fmaf(cf[20+j], __sinf(s), cf[22+j])));
    }

    // level 0: 2 -> 1
    {
        float l = g2[0], r = g2[1];
        float s = l + r;
        out[i] = fmaf(cf[24], s,
                  fmaf(cf[25], l * r,
                   fmaf(cf[26], __sinf(s), cf[27])));
    }
}

extern "C" void kernel_launch(void* const* d_in, const int* in_sizes, int n_in,
                              void* d_out, int out_size, void* d_ws, size_t ws_size,
                              hipStream_t stream) {
    const float* x      = (const float*)d_in[0];
    const float* W_leaf = (const float*)d_in[1];
    const float* b_leaf = (const float*)d_in[2];
    const float* w0     = (const float*)d_in[3];
    const float* w1     = (const float*)d_in[4];
    const float* w2     = (const float*)d_in[5];
    const float* b0     = (const float*)d_in[6];
    const float* b1     = (const float*)d_in[7];
    const float* b2     = (const float*)d_in[8];
    const float* om0    = (const float*)d_in[9];
    const float* om1    = (const float*)d_in[10];
    const float* om2    = (const float*)d_in[11];
    float* out = (float*)d_out;

    int n = in_sizes[0] / 16;
    int block = 256;
    int grid = (n + block - 1) / block;
    tree_rnn_fused<<<grid, block, 0, stream>>>(
        x, W_leaf, b_leaf, w0, w1, w2, b0, b1, b2, om0, om1, om2, out, n);
}